// Round 8
// baseline (250.452 us; speedup 1.0000x reference)
//
#include <hip/hip_runtime.h>
#include <hip/hip_bf16.h>
#include <math.h>

#define D_MODEL 512
#define N_HEADS 8
#define D_K     64
#define T_SEQ   2048
#define B_SZ    4
#define M_ROWS  (B_SZ * T_SEQ)   // 8192

typedef __bf16 bf16;
typedef __bf16 bf16x4 __attribute__((ext_vector_type(4)));
typedef __bf16 bf16x8 __attribute__((ext_vector_type(8)));
typedef float  floatx4 __attribute__((ext_vector_type(4)));

// 16B-atom XOR swizzle for stride-64 bf16 LDS tiles: conflict-free b128
// fragment access (padding cannot fix b128 tiles: stride%4dw==0 -> 8-way).
__device__ __forceinline__ int SWZ(int row, int col) {
  return row * 64 + ((((col >> 3) ^ (row & 7)) << 3) | (col & 7));
}

// ---------------------------------------------------------------------------
// Convert 4 weight matrices (f32, 512x512 each) to bf16. [wq|wk|wv|wo]
// ---------------------------------------------------------------------------
__global__ __launch_bounds__(256) void convert_weights(
    const float* __restrict__ wq, const float* __restrict__ wk,
    const float* __restrict__ wv, const float* __restrict__ wo,
    bf16* __restrict__ dst) {
  int gid = blockIdx.x * 256 + threadIdx.x;
  int e0  = gid * 4;
  int mat = e0 >> 18;
  int loc = e0 & 262143;
  const float* src = (mat == 0) ? wq : (mat == 1) ? wk : (mat == 2) ? wv : wo;
  float4 v = *(const float4*)(src + loc);
  bf16* d = dst + e0;
  d[0] = (bf16)v.x; d[1] = (bf16)v.y; d[2] = (bf16)v.z; d[3] = (bf16)v.w;
}

// ---------------------------------------------------------------------------
// LayerNorm: one block per row (512 f32), f32 in -> bf16 out.
// ---------------------------------------------------------------------------
__global__ __launch_bounds__(256) void ln_kernel(const float* __restrict__ x,
                                                 const float* __restrict__ g,
                                                 const float* __restrict__ b,
                                                 bf16* __restrict__ out) {
  int row = blockIdx.x;
  int tid = threadIdx.x;
  const float* xr = x + (size_t)row * D_MODEL;
  float2 v = *(const float2*)(xr + 2 * tid);
  float s = v.x + v.y, ss = v.x * v.x + v.y * v.y;
  for (int off = 32; off; off >>= 1) {
    s  += __shfl_down(s,  off, 64);
    ss += __shfl_down(ss, off, 64);
  }
  __shared__ float ps[4], pss[4], stats[2];
  int wave = tid >> 6, lane = tid & 63;
  if (lane == 0) { ps[wave] = s; pss[wave] = ss; }
  __syncthreads();
  if (tid == 0) {
    float S  = ps[0] + ps[1] + ps[2] + ps[3];
    float SS = pss[0] + pss[1] + pss[2] + pss[3];
    float mu  = S / (float)D_MODEL;
    float var = SS / (float)D_MODEL - mu * mu;
    stats[0] = mu;
    stats[1] = rsqrtf(var + 1e-5f);
  }
  __syncthreads();
  float mu = stats[0], rs = stats[1];
  float2 gg = *(const float2*)(g + 2 * tid);
  float2 bb = *(const float2*)(b + 2 * tid);
  bf16* orow = out + (size_t)row * D_MODEL;
  orow[2 * tid]     = (bf16)((v.x - mu) * rs * gg.x + bb.x);
  orow[2 * tid + 1] = (bf16)((v.y - mu) * rs * gg.y + bb.y);
}

// ---------------------------------------------------------------------------
// Sinusoidal PE value for (t, d), d in [0,64).
// ---------------------------------------------------------------------------
__device__ __forceinline__ float pe_val(int t, int d) {
  int i2 = d & ~1;
  float div = expf((float)i2 * (-0.1439115683f));  // -ln(10000)/64
  float ang = (float)t * div;
  return (d & 1) ? cosf(ang) : sinf(ang);
}

// ---------------------------------------------------------------------------
// QKV projection GEMM — direct-from-global K-loop (barrier-free; compiler
// pipelines the loads with fine vmcnt — measured 92us vs 104us staged).
// Grid (64, 24): block = 128m x 64n of ONE matrix (by>>3: 0=Q,1=K,2=V),
// head h = by&7. Wave: 32m x 64n, acc[2][4].
// Epilogue via wave-private LDS transpose -> full-line b128 stores
// (R5's scattered 2B stores caused 2.3x write amplification):
//   Q: (acc+bq)*0.125 -> Qb[bh][t][d]
//   K: acc+bk+pe      -> Kb[bh][t][d]
//   V: acc+bv         -> VT[bh][d][t]
// ---------------------------------------------------------------------------
__global__ __launch_bounds__(256, 4) void gemm_qkv(
    const bf16* __restrict__ A, const bf16* __restrict__ wqkv,
    const float* __restrict__ bq, const float* __restrict__ bk, const float* __restrict__ bv,
    bf16* __restrict__ Qo, bf16* __restrict__ Ko, bf16* __restrict__ VTo) {
  __shared__ bf16 ep[4][2560];           // 20 KB epilogue scratch
  int wave = threadIdx.x >> 6, lane = threadIdx.x & 63;
  int lm = lane & 15, quad = lane >> 4;
  int n0g  = blockIdx.y * 64;            // 0..1535
  int mat  = n0g >> 9;                   // 0=Q,1=K,2=V
  int nloc = n0g & 511;                  // h*64
  int h    = nloc >> 6;
  const bf16* W = wqkv + (size_t)mat * D_MODEL * D_MODEL;
  int m0 = blockIdx.x * 128 + wave * 32;
  const bf16* ap0 = A + (size_t)(m0 + lm) * D_MODEL + quad * 8;
  const bf16* ap1 = ap0 + (size_t)16 * D_MODEL;
  const bf16* bp0 = W + (size_t)(nloc + lm) * D_MODEL + quad * 8;

  floatx4 acc[2][4];
#pragma unroll
  for (int mi = 0; mi < 2; mi++)
#pragma unroll
    for (int nt = 0; nt < 4; nt++) acc[mi][nt] = floatx4{0.f, 0.f, 0.f, 0.f};
#pragma unroll
  for (int k = 0; k < D_MODEL; k += 32) {
    bf16x8 a0 = *(const bf16x8*)(ap0 + k);
    bf16x8 a1 = *(const bf16x8*)(ap1 + k);
#pragma unroll
    for (int nt = 0; nt < 4; nt++) {
      bf16x8 bfr = *(const bf16x8*)(bp0 + (size_t)nt * 16 * D_MODEL + k);
      acc[0][nt] = __builtin_amdgcn_mfma_f32_16x16x32_bf16(a0, bfr, acc[0][nt], 0, 0, 0);
      acc[1][nt] = __builtin_amdgcn_mfma_f32_16x16x32_bf16(a1, bfr, acc[1][nt], 0, 0, 0);
    }
  }

  int bb = m0 >> 11, t0 = m0 & (T_SEQ - 1);   // this wave's 32-t slice start
  size_t bhoff = (size_t)(bb * N_HEADS + h) * (T_SEQ * D_K);
  bf16* myep = ep[wave];

  if (mat == 2) {
    // ---- V -> VT[bh][d][t]: tile [64 d][32 t], stride 40 ----
#pragma unroll
    for (int nt = 0; nt < 4; nt++) {
      int d = nt * 16 + lm;
      float bvv = bv[nloc + d];
#pragma unroll
      for (int mi = 0; mi < 2; mi++) {
        bf16x4 pk;
#pragma unroll
        for (int rr = 0; rr < 4; rr++) pk[rr] = (bf16)(acc[mi][nt][rr] + bvv);
        *(bf16x4*)&myep[d * 40 + mi * 16 + quad * 4] = pk;
      }
    }
#pragma unroll
    for (int rd = 0; rd < 4; rd++) {
      int d = rd * 16 + (lane >> 2);
      bf16x8 v = *(const bf16x8*)&myep[d * 40 + (lane & 3) * 8];
      *(bf16x8*)(VTo + bhoff + (size_t)d * T_SEQ + t0 + (lane & 3) * 8) = v;
    }
  } else {
    // ---- Q or K -> [bh][t][d]: tile [32 t][64 d], stride 72 ----
    bf16* dst = (mat == 0) ? Qo : Ko;
    const float* bias = (mat == 0) ? bq : bk;
#pragma unroll
    for (int nt = 0; nt < 4; nt++) {
      int d = nt * 16 + lm;
      float bval = bias[nloc + d];
#pragma unroll
      for (int mi = 0; mi < 2; mi++) {
#pragma unroll
        for (int rr = 0; rr < 4; rr++) {
          int tl = mi * 16 + quad * 4 + rr;
          float v = acc[mi][nt][rr] + bval;
          if (mat == 1) v += pe_val(t0 + tl, d);
          else          v *= 0.125f;   // fold 1/sqrt(dk) into Q
          myep[tl * 72 + d] = (bf16)v;
        }
      }
    }
#pragma unroll
    for (int rd = 0; rd < 4; rd++) {
      int row = rd * 8 + (lane >> 3);
      bf16x8 v = *(const bf16x8*)&myep[row * 72 + (lane & 7) * 8];
      *(bf16x8*)(dst + bhoff + (size_t)(t0 + row) * D_K + (lane & 7) * 8) = v;
    }
  }
}

// ---------------------------------------------------------------------------
// Output projection GEMM — direct-from-global (reverted): out f32 = ctx@wo^T+bo
// Grid (64, 8): block 128m x 64n, wave 32m x 64n, acc[2][4]. f32 stores are
// naturally full-line (16 lanes x 4B = 64B).
// ---------------------------------------------------------------------------
__global__ __launch_bounds__(256, 4) void gemm_out(const bf16* __restrict__ A,
                                                   const bf16* __restrict__ W,
                                                   const float* __restrict__ bias,
                                                   float* __restrict__ out) {
  int wave = threadIdx.x >> 6, lane = threadIdx.x & 63;
  int lm = lane & 15, quad = lane >> 4;
  int n0 = blockIdx.y * 64;
  int m0 = blockIdx.x * 128 + wave * 32;
  const bf16* ap0 = A + (size_t)(m0 + lm) * D_MODEL + quad * 8;
  const bf16* ap1 = ap0 + (size_t)16 * D_MODEL;
  const bf16* bp0 = W + (size_t)(n0 + lm) * D_MODEL + quad * 8;
  floatx4 acc[2][4];
#pragma unroll
  for (int mi = 0; mi < 2; mi++)
#pragma unroll
    for (int nt = 0; nt < 4; nt++) acc[mi][nt] = floatx4{0.f, 0.f, 0.f, 0.f};
#pragma unroll
  for (int k = 0; k < D_MODEL; k += 32) {
    bf16x8 a0 = *(const bf16x8*)(ap0 + k);
    bf16x8 a1 = *(const bf16x8*)(ap1 + k);
#pragma unroll
    for (int nt = 0; nt < 4; nt++) {
      bf16x8 bfr = *(const bf16x8*)(bp0 + (size_t)nt * 16 * D_MODEL + k);
      acc[0][nt] = __builtin_amdgcn_mfma_f32_16x16x32_bf16(a0, bfr, acc[0][nt], 0, 0, 0);
      acc[1][nt] = __builtin_amdgcn_mfma_f32_16x16x32_bf16(a1, bfr, acc[1][nt], 0, 0, 0);
    }
  }
#pragma unroll
  for (int nt = 0; nt < 4; nt++) {
    int n = n0 + nt * 16 + lm;
    float bval = bias[n];
#pragma unroll
    for (int mi = 0; mi < 2; mi++)
#pragma unroll
      for (int rr = 0; rr < 4; rr++) {
        int m = m0 + mi * 16 + quad * 4 + rr;
        out[(size_t)m * D_MODEL + n] = acc[mi][nt][rr] + bval;
      }
  }
}

// ---------------------------------------------------------------------------
// MFMA flash attention v3: v2 + register-prefetch double-buffering of the
// K/V^T staging (tile kt+1 loaded into VGPRs right after tile kt's LDS write;
// the vmcnt wait then lands after the compute section instead of inside the
// barrier pair, hiding the ~200-900cyc global latency).
// ---------------------------------------------------------------------------
__global__ __launch_bounds__(256) void flash_mfma(const bf16* __restrict__ Q,
                                                  const bf16* __restrict__ K,
                                                  const bf16* __restrict__ VT,
                                                  bf16* __restrict__ ctx) {
  __shared__ bf16 sK[64 * 64];          // [key][d]   8 KB, swizzled
  __shared__ bf16 sVT[64 * 64];         // [d][key]   8 KB, swizzled
  __shared__ bf16 sP[4][32 * 64];       // per-wave [q][key] 16 KB, swizzled

  int tid  = threadIdx.x;
  int wave = tid >> 6, lane = tid & 63;
  int lm = lane & 15, quad = lane >> 4;
  int bh = blockIdx.y;
  int q0 = blockIdx.x * 128 + wave * 32;

  const bf16* Qb  = Q  + (size_t)bh * T_SEQ * D_K;
  const bf16* Kb  = K  + (size_t)bh * T_SEQ * D_K;
  const bf16* VTb = VT + (size_t)bh * T_SEQ * D_K;  // [d][t]

  bf16x8 qf[2][2];
#pragma unroll
  for (int qt = 0; qt < 2; qt++)
#pragma unroll
    for (int kb = 0; kb < 2; kb++)
      qf[qt][kb] = *(const bf16x8*)(Qb + (size_t)(q0 + qt * 16 + lm) * D_K + kb * 32 + quad * 8);

  floatx4 o[2][4];
#pragma unroll
  for (int qt = 0; qt < 2; qt++)
#pragma unroll
    for (int nt = 0; nt < 4; nt++) o[qt][nt] = floatx4{0.f, 0.f, 0.f, 0.f};
  float l_i[2] = {0.f, 0.f};

  int srow = wave * 16 + (lane >> 2);
  int scol = (lane & 3) * 16;
  const bf16* kp0 = Kb  + (size_t)srow * D_K + scol;
  const bf16* vp0 = VTb + (size_t)srow * T_SEQ + scol;

  // prefetch tile 0
  bf16x8 rk0 = *(const bf16x8*)(kp0);
  bf16x8 rk1 = *(const bf16x8*)(kp0 + 8);
  bf16x8 rv0 = *(const bf16x8*)(vp0);
  bf16x8 rv1 = *(const bf16x8*)(vp0 + 8);

  for (int kt = 0; kt < T_SEQ / 64; kt++) {
    __syncthreads();                 // prior tile fully consumed
    *(bf16x8*)&sK[SWZ(srow, scol)]      = rk0;
    *(bf16x8*)&sK[SWZ(srow, scol + 8)]  = rk1;
    *(bf16x8*)&sVT[SWZ(srow, scol)]     = rv0;
    *(bf16x8*)&sVT[SWZ(srow, scol + 8)] = rv1;
    if (kt + 1 < T_SEQ / 64) {       // issue next-tile loads; wait deferred
      const bf16* kp = kp0 + (size_t)(kt + 1) * 64 * D_K;
      const bf16* vp = vp0 + (size_t)(kt + 1) * 64;
      rk0 = *(const bf16x8*)(kp);
      rk1 = *(const bf16x8*)(kp + 8);
      rv0 = *(const bf16x8*)(vp);
      rv1 = *(const bf16x8*)(vp + 8);
    }
    __syncthreads();                 // tile visible to all waves

    floatx4 s[2][4];
#pragma unroll
    for (int qt = 0; qt < 2; qt++)
#pragma unroll
      for (int nt = 0; nt < 4; nt++) s[qt][nt] = floatx4{0.f, 0.f, 0.f, 0.f};
#pragma unroll
    for (int kb = 0; kb < 2; kb++) {
#pragma unroll
      for (int nt = 0; nt < 4; nt++) {
        bf16x8 kf = *(const bf16x8*)&sK[SWZ(nt * 16 + lm, kb * 32 + quad * 8)];
        s[0][nt] = __builtin_amdgcn_mfma_f32_16x16x32_bf16(kf, qf[0][kb], s[0][nt], 0, 0, 0);
        s[1][nt] = __builtin_amdgcn_mfma_f32_16x16x32_bf16(kf, qf[1][kb], s[1][nt], 0, 0, 0);
      }
    }

#pragma unroll
    for (int qt = 0; qt < 2; qt++) {
      float ls = 0.f;
      bf16x4 pk[4];
#pragma unroll
      for (int nt = 0; nt < 4; nt++) {
#pragma unroll
        for (int rr = 0; rr < 4; rr++) {
          float p = __expf(s[qt][nt][rr] - 8.0f);
          ls += p;
          pk[nt][rr] = (bf16)p;
        }
      }
#pragma unroll
      for (int nt = 0; nt < 4; nt++)
        *(bf16x4*)&sP[wave][SWZ(qt * 16 + lm, nt * 16 + quad * 4)] = pk[nt];
      ls += __shfl_xor(ls, 16, 64);
      ls += __shfl_xor(ls, 32, 64);
      l_i[qt] += ls;
    }
    // per-wave-private sP: same-wave DS ordering, no barrier needed

#pragma unroll
    for (int kb = 0; kb < 2; kb++) {
      bf16x8 pf0 = *(const bf16x8*)&sP[wave][SWZ(lm, kb * 32 + quad * 8)];
      bf16x8 pf1 = *(const bf16x8*)&sP[wave][SWZ(16 + lm, kb * 32 + quad * 8)];
#pragma unroll
      for (int nt = 0; nt < 4; nt++) {
        bf16x8 vt = *(const bf16x8*)&sVT[SWZ(nt * 16 + lm, kb * 32 + quad * 8)];
        o[0][nt] = __builtin_amdgcn_mfma_f32_16x16x32_bf16(pf0, vt, o[0][nt], 0, 0, 0);
        o[1][nt] = __builtin_amdgcn_mfma_f32_16x16x32_bf16(pf1, vt, o[1][nt], 0, 0, 0);
      }
    }
  }

  int b_ = bh >> 3, h = bh & 7;
#pragma unroll
  for (int qt = 0; qt < 2; qt++) {
#pragma unroll
    for (int rr = 0; rr < 4; rr++) {
      int qq = quad * 4 + rr;
      float linv = 1.f / __shfl(l_i[qt], qq, 64);
      int t = q0 + qt * 16 + qq;
      bf16* op = ctx + ((size_t)(b_ * T_SEQ + t)) * D_MODEL + h * D_K;
#pragma unroll
      for (int nt = 0; nt < 4; nt++)
        op[nt * 16 + lm] = (bf16)(o[qt][nt][rr] * linv);
    }
  }
}

// ---------------------------------------------------------------------------
extern "C" void kernel_launch(void* const* d_in, const int* in_sizes, int n_in,
                              void* d_out, int out_size, void* d_ws, size_t ws_size,
                              hipStream_t stream) {
  const float* x    = (const float*)d_in[0];
  const float* ln_g = (const float*)d_in[1];
  const float* ln_b = (const float*)d_in[2];
  const float* wq   = (const float*)d_in[3];
  const float* bq   = (const float*)d_in[4];
  const float* wk   = (const float*)d_in[5];
  const float* bk   = (const float*)d_in[6];
  const float* wv   = (const float*)d_in[7];
  const float* bv   = (const float*)d_in[8];
  const float* wo   = (const float*)d_in[9];
  const float* bo   = (const float*)d_in[10];
  float* out = (float*)d_out;

  char* ws = (char*)d_ws;
  const size_t MB8 = (size_t)M_ROWS * D_MODEL * sizeof(bf16);  // 8 MB
  bf16* normed = (bf16*)(ws);                    // dead after gemm_qkv
  bf16* Qb     = (bf16*)(ws + MB8);
  bf16* Kb     = (bf16*)(ws + 2 * MB8);
  bf16* VTb    = (bf16*)(ws + 3 * MB8);          // V^T: [bh][d][t]
  bf16* w4     = (bf16*)(ws + 4 * MB8);          // 2 MB: wq|wk|wv|wo bf16
  bf16* ctx    = normed;                         // alias; ws total 34 MB

  convert_weights<<<1024, 256, 0, stream>>>(wq, wk, wv, wo, w4);
  ln_kernel<<<M_ROWS, 256, 0, stream>>>(x, ln_g, ln_b, normed);
  gemm_qkv<<<dim3(M_ROWS / 128, 24), 256, 0, stream>>>(
      normed, w4, bq, bk, bv, Qb, Kb, VTb);
  flash_mfma<<<dim3(T_SEQ / 128, B_SZ * N_HEADS), 256, 0, stream>>>(Qb, Kb, VTb, ctx);
  gemm_out<<<dim3(M_ROWS / 128, D_MODEL / 64), 256, 0, stream>>>(
      ctx, w4 + 3 * (size_t)D_MODEL * D_MODEL, bo, out);
}